// Round 2
// baseline (408.461 us; speedup 1.0000x reference)
//
#include <hip/hip_runtime.h>
#include <hip/hip_bf16.h>
#include <cstdint>

// VanillaLSTMCell: B=8192, I=H=1024.
// z = [x|h] @ [Wx;Wh]^T + b  (M=8192, N=4096, K=2048).
// W packed GATE-INTERLEAVED: n = 4*j + gate (gate: 0=i,1=f,2=o,3=g) so each
// 128-wide z-tile holds all 4 gates for 32 output columns -> LSTM pointwise
// fused into the GEMM epilogue (no Z buffer, no pointwise kernel).

typedef __bf16 bf16;
typedef __attribute__((ext_vector_type(8))) bf16 bf16x8;
typedef __attribute__((ext_vector_type(4))) bf16 bf16x4;
typedef __attribute__((ext_vector_type(4))) float f32x4;

#define BM 128
#define BN 128
#define BK 32

__device__ __forceinline__ void gload_lds16(const void* g, void* l) {
  __builtin_amdgcn_global_load_lds(
      (__attribute__((address_space(1))) void*)(void*)(g),
      (__attribute__((address_space(3))) void*)(void*)(l),
      16, 0, 0);
}

// ---- pack x|h -> A_bf16 [8192][2048], K-contiguous ----
__global__ __launch_bounds__(256) void pack_a(const float* __restrict__ x,
                                              const float* __restrict__ h,
                                              bf16* __restrict__ A) {
  int idx = blockIdx.x * 256 + threadIdx.x;
  int m  = idx >> 9;
  int k  = (idx & 511) * 4;
  const float* src = (k < 1024) ? (x + (size_t)m * 1024 + k)
                                : (h + (size_t)m * 1024 + (k - 1024));
  f32x4 v = *(const f32x4*)src;
  bf16x4 o;
  o[0] = (bf16)v[0]; o[1] = (bf16)v[1]; o[2] = (bf16)v[2]; o[3] = (bf16)v[3];
  *(bf16x4*)(A + (size_t)idx * 4) = o;
}

// ---- pack weights gate-INTERLEAVED: W[n][k], n = 4*j + gate; also Bcomb ----
__global__ __launch_bounds__(256) void pack_w(
    const float* __restrict__ wxi, const float* __restrict__ whi,
    const float* __restrict__ wxf, const float* __restrict__ whf,
    const float* __restrict__ wxo, const float* __restrict__ who,
    const float* __restrict__ wxg, const float* __restrict__ whg,
    const float* __restrict__ bxi, const float* __restrict__ bhi,
    const float* __restrict__ bxf, const float* __restrict__ bhf,
    const float* __restrict__ bxo, const float* __restrict__ bho,
    const float* __restrict__ bxg, const float* __restrict__ bhg,
    bf16* __restrict__ W, float* __restrict__ Bcomb) {
  int idx = blockIdx.x * 256 + threadIdx.x;   // 2,097,152 groups of 4
  int n  = idx >> 9;
  int k  = (idx & 511) * 4;
  int gate = n & 3;
  int j    = n >> 2;
  const float* wx = (gate == 0) ? wxi : (gate == 1) ? wxf : (gate == 2) ? wxo : wxg;
  const float* wh = (gate == 0) ? whi : (gate == 1) ? whf : (gate == 2) ? who : whg;
  const float* src = (k < 1024) ? (wx + (size_t)j * 1024 + k)
                                : (wh + (size_t)j * 1024 + (k - 1024));
  f32x4 v = *(const f32x4*)src;
  bf16x4 o;
  o[0] = (bf16)v[0]; o[1] = (bf16)v[1]; o[2] = (bf16)v[2]; o[3] = (bf16)v[3];
  *(bf16x4*)(W + (size_t)idx * 4) = o;
  if ((idx & 511) == 0) {
    const float* bx = (gate == 0) ? bxi : (gate == 1) ? bxf : (gate == 2) ? bxo : bxg;
    const float* bh = (gate == 0) ? bhi : (gate == 1) ? bhf : (gate == 2) ? bho : bhg;
    Bcomb[n] = bx[j] + bh[j];
  }
}

__device__ __forceinline__ float sigf(float v) { return 1.f / (1.f + __expf(-v)); }
__device__ __forceinline__ float tanhfast(float v) {
  v = fminf(15.f, fmaxf(-15.f, v));
  float e = __expf(2.f * v);
  return (e - 1.f) / (e + 1.f);
}

// ---- fused bf16 NT GEMM + LSTM pointwise epilogue ----
__global__ __launch_bounds__(256) void gemm_lstm(const bf16* __restrict__ A,
                                                 const bf16* __restrict__ W,
                                                 const float* __restrict__ Bcomb,
                                                 const float* __restrict__ c,
                                                 float* __restrict__ out) {
  constexpr int K = 2048;
  __shared__ __align__(16) bf16 As[BM * BK];        // 8 KB
  __shared__ __align__(16) bf16 Bs[BN * BK];        // 8 KB
  __shared__ __align__(16) float Es[4][16 * 68];    // 17 KB epilogue transpose

  const int t    = threadIdx.x;
  const int wave = t >> 6;
  const int lane = t & 63;
  const int m0 = blockIdx.y * BM;
  const int n0 = blockIdx.x * BN;
  const int wm = (wave >> 1) * 64;
  const int wn = (wave & 1) * 64;
  const int lrow = lane & 15;
  const int lkg  = lane >> 4;

  f32x4 acc[4][4] = {};

  const int arow = t >> 2;
  const int acol = (t & 3) * 8;
  const bf16* gA0 = A + (size_t)(m0 + arow) * K + acol;
  const bf16* gA1 = A + (size_t)(m0 + 64 + arow) * K + acol;
  const bf16* gB0 = W + (size_t)(n0 + arow) * K + acol;
  const bf16* gB1 = W + (size_t)(n0 + 64 + arow) * K + acol;
  bf16* lA0 = &As[t * 8];
  bf16* lA1 = &As[2048 + t * 8];
  bf16* lB0 = &Bs[t * 8];
  bf16* lB1 = &Bs[2048 + t * 8];

  for (int kt = 0; kt < K; kt += BK) {
    gload_lds16(gA0 + kt, lA0);
    gload_lds16(gA1 + kt, lA1);
    gload_lds16(gB0 + kt, lB0);
    gload_lds16(gB1 + kt, lB1);
    __syncthreads();

    bf16x8 a[4], b[4];
#pragma unroll
    for (int i = 0; i < 4; ++i) {
      a[i] = *(const bf16x8*)&As[(wm + i * 16 + lrow) * BK + lkg * 8];
      b[i] = *(const bf16x8*)&Bs[(wn + i * 16 + lrow) * BK + lkg * 8];
    }
#pragma unroll
    for (int mi = 0; mi < 4; ++mi)
#pragma unroll
      for (int ni = 0; ni < 4; ++ni)
        acc[mi][ni] = __builtin_amdgcn_mfma_f32_16x16x32_bf16(a[mi], b[ni], acc[mi][ni], 0, 0, 0);
    __syncthreads();
  }

  // Epilogue: per 16-row slab, transpose wave's 16x64 f32 through padded LDS
  // (stride 68 f32 -> ds_write 2-way aliasing = free; ds_read_b128 16B-aligned),
  // then each (row,j) item = 4 contiguous gate values -> LSTM pointwise.
  const int jbase = blockIdx.x * 32 + (wn >> 2);
  float* E = Es[wave];
#pragma unroll
  for (int mi = 0; mi < 4; ++mi) {
    __syncthreads();
#pragma unroll
    for (int ni = 0; ni < 4; ++ni)
#pragma unroll
      for (int r = 0; r < 4; ++r)
        E[(lkg * 4 + r) * 68 + ni * 16 + lrow] = acc[mi][ni][r];
    __syncthreads();
#pragma unroll
    for (int rr = 0; rr < 4; ++rr) {
      int item = rr * 64 + lane;
      int rl = item >> 4;       // 0..15 local row
      int jl = item & 15;       // 0..15 local j
      f32x4 z4 = *(const f32x4*)&E[rl * 68 + jl * 4];
      int jg = jbase + jl;
      f32x4 b4 = *(const f32x4*)&Bcomb[jg * 4];
      int rowg = m0 + wm + mi * 16 + rl;
      float zi = z4[0] + b4[0];
      float zf = z4[1] + b4[1];
      float zo = z4[2] + b4[2];
      float zg = z4[3] + b4[3];
      float cv = c[(size_t)rowg * 1024 + jg];
      float it = sigf(zi), ft = sigf(zf), ot = sigf(zo), gt = tanhfast(zg);
      float cn = ft * cv + it * gt;
      out[(size_t)rowg * 1024 + jg] = ot * tanhfast(cn);           // h_next
      out[(size_t)8388608 + (size_t)rowg * 1024 + jg] = cn;        // c_next
    }
  }
}

extern "C" void kernel_launch(void* const* d_in, const int* in_sizes, int n_in,
                              void* d_out, int out_size, void* d_ws, size_t ws_size,
                              hipStream_t stream) {
  const float* x   = (const float*)d_in[0];
  const float* h   = (const float*)d_in[1];
  const float* c   = (const float*)d_in[2];
  const float* Wxi = (const float*)d_in[3];  const float* bxi = (const float*)d_in[4];
  const float* Whi = (const float*)d_in[5];  const float* bhi = (const float*)d_in[6];
  const float* Wxf = (const float*)d_in[7];  const float* bxf = (const float*)d_in[8];
  const float* Whf = (const float*)d_in[9];  const float* bhf = (const float*)d_in[10];
  const float* Wxo = (const float*)d_in[11]; const float* bxo = (const float*)d_in[12];
  const float* Who = (const float*)d_in[13]; const float* bho = (const float*)d_in[14];
  const float* Wxg = (const float*)d_in[15]; const float* bxg = (const float*)d_in[16];
  const float* Whg = (const float*)d_in[17]; const float* bhg = (const float*)d_in[18];
  float* out = (float*)d_out;

  // workspace: A_bf16 [8192*2048] (32MB) + W_bf16 [4096*2048] (16MB) + Bcomb (16KB)
  bf16*  Abuf  = (bf16*)d_ws;
  bf16*  Wbuf  = Abuf + (size_t)8192 * 2048;
  float* Bcomb = (float*)(Wbuf + (size_t)4096 * 2048);

  pack_a<<<16384, 256, 0, stream>>>(x, h, Abuf);
  pack_w<<<8192, 256, 0, stream>>>(Wxi, Whi, Wxf, Whf, Wxo, Who, Wxg, Whg,
                                   bxi, bhi, bxf, bhf, bxo, bho, bxg, bhg,
                                   Wbuf, Bcomb);
  gemm_lstm<<<dim3(32, 64), 256, 0, stream>>>(Abuf, Wbuf, Bcomb, c, out);
}

// Round 3
// 402.012 us; speedup vs baseline: 1.0160x; 1.0160x over previous
//
#include <hip/hip_runtime.h>
#include <hip/hip_bf16.h>
#include <cstdint>

// VanillaLSTMCell: B=8192, I=H=1024.
// z = [x|h] @ [Wx;Wh]^T + b  (M=8192, N=4096, K=2048).
// W packed GATE-INTERLEAVED: n = 4*j + gate (0=i,1=f,2=o,3=g) -> LSTM pointwise
// fused into GEMM epilogue. Epilogue transposes through LDS OVERLAID on the
// dead As/Bs staging buffers; per-lane mapping is (row, 4 consecutive j) so
// c-loads and h/c-stores are f32x4-coalesced.

typedef __bf16 bf16;
typedef __attribute__((ext_vector_type(8))) bf16 bf16x8;
typedef __attribute__((ext_vector_type(4))) bf16 bf16x4;
typedef __attribute__((ext_vector_type(4))) float f32x4;

#define BM 128
#define BN 128
#define BK 32
#define CN_OFF 8388608  // 8192*1024, c_next offset in d_out

__device__ __forceinline__ void gload_lds16(const void* g, void* l) {
  __builtin_amdgcn_global_load_lds(
      (__attribute__((address_space(1))) void*)(void*)(g),
      (__attribute__((address_space(3))) void*)(void*)(l),
      16, 0, 0);
}

// ---- single pack kernel: blocks [0,16384) pack A; [16384,24576) pack W (+bias) ----
__global__ __launch_bounds__(256) void pack_all(
    const float* __restrict__ x, const float* __restrict__ h,
    const float* __restrict__ wxi, const float* __restrict__ whi,
    const float* __restrict__ wxf, const float* __restrict__ whf,
    const float* __restrict__ wxo, const float* __restrict__ who,
    const float* __restrict__ wxg, const float* __restrict__ whg,
    const float* __restrict__ bxi, const float* __restrict__ bhi,
    const float* __restrict__ bxf, const float* __restrict__ bhf,
    const float* __restrict__ bxo, const float* __restrict__ bho,
    const float* __restrict__ bxg, const float* __restrict__ bhg,
    bf16* __restrict__ A, bf16* __restrict__ W, float* __restrict__ Bcomb) {
  int b = blockIdx.x;
  if (b < 16384) {
    int idx = b * 256 + threadIdx.x;          // A: [8192][2048]
    int m = idx >> 9;
    int k = (idx & 511) * 4;
    const float* src = (k < 1024) ? (x + (size_t)m * 1024 + k)
                                  : (h + (size_t)m * 1024 + (k - 1024));
    f32x4 v = *(const f32x4*)src;
    bf16x4 o;
    o[0] = (bf16)v[0]; o[1] = (bf16)v[1]; o[2] = (bf16)v[2]; o[3] = (bf16)v[3];
    *(bf16x4*)(A + (size_t)idx * 4) = o;
  } else {
    int idx = (b - 16384) * 256 + threadIdx.x; // W: [4096][2048], n = 4*j+gate
    int n = idx >> 9;
    int k = (idx & 511) * 4;
    int gate = n & 3;
    int j    = n >> 2;
    const float* wx = (gate == 0) ? wxi : (gate == 1) ? wxf : (gate == 2) ? wxo : wxg;
    const float* wh = (gate == 0) ? whi : (gate == 1) ? whf : (gate == 2) ? who : whg;
    const float* src = (k < 1024) ? (wx + (size_t)j * 1024 + k)
                                  : (wh + (size_t)j * 1024 + (k - 1024));
    f32x4 v = *(const f32x4*)src;
    bf16x4 o;
    o[0] = (bf16)v[0]; o[1] = (bf16)v[1]; o[2] = (bf16)v[2]; o[3] = (bf16)v[3];
    *(bf16x4*)(W + (size_t)idx * 4) = o;
    if ((idx & 511) == 0) {
      const float* bx = (gate == 0) ? bxi : (gate == 1) ? bxf : (gate == 2) ? bxo : bxg;
      const float* bh = (gate == 0) ? bhi : (gate == 1) ? bhf : (gate == 2) ? bho : bhg;
      Bcomb[n] = bx[j] + bh[j];
    }
  }
}

__device__ __forceinline__ float sigf(float v) { return 1.f / (1.f + __expf(-v)); }
__device__ __forceinline__ float tanhfast(float v) {
  v = fminf(15.f, fmaxf(-15.f, v));
  float e = __expf(2.f * v);
  return (e - 1.f) / (e + 1.f);
}

// ---- fused bf16 NT GEMM + LSTM pointwise epilogue ----
__global__ __launch_bounds__(256) void gemm_lstm(const bf16* __restrict__ A,
                                                 const bf16* __restrict__ W,
                                                 const float* __restrict__ Bcomb,
                                                 const float* __restrict__ c,
                                                 float* __restrict__ out) {
  constexpr int K = 2048;
  // 17408 B shared region: K-loop uses As(8K)+Bs(8K); epilogue overlays
  // 4 per-wave transpose buffers of 16*68 f32 (4352 B each).
  __shared__ __align__(16) char smem[4 * 4352];
  bf16* As = (bf16*)smem;
  bf16* Bs = (bf16*)(smem + 8192);

  const int t    = threadIdx.x;
  const int wave = t >> 6;
  const int lane = t & 63;
  const int m0 = blockIdx.y * BM;
  const int n0 = blockIdx.x * BN;
  const int wm = (wave >> 1) * 64;
  const int wn = (wave & 1) * 64;
  const int lrow = lane & 15;
  const int lkg  = lane >> 4;

  f32x4 acc[4][4] = {};

  const int arow = t >> 2;
  const int acol = (t & 3) * 8;
  const bf16* gA0 = A + (size_t)(m0 + arow) * K + acol;
  const bf16* gA1 = A + (size_t)(m0 + 64 + arow) * K + acol;
  const bf16* gB0 = W + (size_t)(n0 + arow) * K + acol;
  const bf16* gB1 = W + (size_t)(n0 + 64 + arow) * K + acol;
  bf16* lA0 = &As[t * 8];
  bf16* lA1 = &As[2048 + t * 8];
  bf16* lB0 = &Bs[t * 8];
  bf16* lB1 = &Bs[2048 + t * 8];

  for (int kt = 0; kt < K; kt += BK) {
    gload_lds16(gA0 + kt, lA0);
    gload_lds16(gA1 + kt, lA1);
    gload_lds16(gB0 + kt, lB0);
    gload_lds16(gB1 + kt, lB1);
    __syncthreads();

    bf16x8 a[4], b[4];
#pragma unroll
    for (int i = 0; i < 4; ++i) {
      a[i] = *(const bf16x8*)&As[(wm + i * 16 + lrow) * BK + lkg * 8];
      b[i] = *(const bf16x8*)&Bs[(wn + i * 16 + lrow) * BK + lkg * 8];
    }
#pragma unroll
    for (int mi = 0; mi < 4; ++mi)
#pragma unroll
      for (int ni = 0; ni < 4; ++ni)
        acc[mi][ni] = __builtin_amdgcn_mfma_f32_16x16x32_bf16(a[mi], b[ni], acc[mi][ni], 0, 0, 0);
    __syncthreads();
  }

  // ---- fused LSTM epilogue ----
  // Wave covers rows [wm+mi*16, +16) x j in [jbase, jbase+16).
  // Lane mapping: rl = lane>>2 (row 0..15), jl4 = (lane&3)*4 (4 consecutive j).
  // c-load f32x4 / stores f32x4 coalesced; z read as 4x ds_read_b128 of
  // 16 contiguous gate floats from the 68-stride transpose buffer.
  const int jbase = blockIdx.x * 32 + (wn >> 2);
  const int rl  = lane >> 2;
  const int jl4 = (lane & 3) * 4;
  float* E = (float*)(smem + wave * 4352);

  f32x4 bias[4];
#pragma unroll
  for (int jj = 0; jj < 4; ++jj)
    bias[jj] = *(const f32x4*)&Bcomb[(jbase + jl4 + jj) * 4];

#pragma unroll
  for (int mi = 0; mi < 4; ++mi) {
    const int rowg = m0 + wm + mi * 16 + rl;
    f32x4 cv = *(const f32x4*)&c[(size_t)rowg * 1024 + jbase + jl4];  // early issue

    __syncthreads();   // E region free (prev slab read / As-Bs dead)
#pragma unroll
    for (int ni = 0; ni < 4; ++ni)
#pragma unroll
      for (int r = 0; r < 4; ++r)
        E[(lkg * 4 + r) * 68 + ni * 16 + lrow] = acc[mi][ni][r];
    __syncthreads();

    f32x4 hv, cn;
#pragma unroll
    for (int jj = 0; jj < 4; ++jj) {
      f32x4 z4 = *(const f32x4*)&E[rl * 68 + (jl4 + jj) * 4];  // gates i,f,o,g
      float zi = z4[0] + bias[jj][0];
      float zf = z4[1] + bias[jj][1];
      float zo = z4[2] + bias[jj][2];
      float zg = z4[3] + bias[jj][3];
      float it = sigf(zi), ft = sigf(zf), ot = sigf(zo), gt = tanhfast(zg);
      float cnext = ft * cv[jj] + it * gt;
      cn[jj] = cnext;
      hv[jj] = ot * tanhfast(cnext);
    }
    *(f32x4*)&out[(size_t)rowg * 1024 + jbase + jl4] = hv;
    *(f32x4*)&out[(size_t)CN_OFF + (size_t)rowg * 1024 + jbase + jl4] = cn;
  }
}

extern "C" void kernel_launch(void* const* d_in, const int* in_sizes, int n_in,
                              void* d_out, int out_size, void* d_ws, size_t ws_size,
                              hipStream_t stream) {
  const float* x   = (const float*)d_in[0];
  const float* h   = (const float*)d_in[1];
  const float* c   = (const float*)d_in[2];
  const float* Wxi = (const float*)d_in[3];  const float* bxi = (const float*)d_in[4];
  const float* Whi = (const float*)d_in[5];  const float* bhi = (const float*)d_in[6];
  const float* Wxf = (const float*)d_in[7];  const float* bxf = (const float*)d_in[8];
  const float* Whf = (const float*)d_in[9];  const float* bhf = (const float*)d_in[10];
  const float* Wxo = (const float*)d_in[11]; const float* bxo = (const float*)d_in[12];
  const float* Who = (const float*)d_in[13]; const float* bho = (const float*)d_in[14];
  const float* Wxg = (const float*)d_in[15]; const float* bxg = (const float*)d_in[16];
  const float* Whg = (const float*)d_in[17]; const float* bhg = (const float*)d_in[18];
  float* out = (float*)d_out;

  bf16*  Abuf  = (bf16*)d_ws;                          // 32 MB
  bf16*  Wbuf  = Abuf + (size_t)8192 * 2048;           // 16 MB
  float* Bcomb = (float*)(Wbuf + (size_t)4096 * 2048); // 16 KB

  pack_all<<<24576, 256, 0, stream>>>(x, h,
                                      Wxi, Whi, Wxf, Whf, Wxo, Who, Wxg, Whg,
                                      bxi, bhi, bxf, bhf, bxo, bho, bxg, bhg,
                                      Abuf, Wbuf, Bcomb);
  gemm_lstm<<<dim3(32, 64), 256, 0, stream>>>(Abuf, Wbuf, Bcomb, c, out);
}

// Round 4
// 378.319 us; speedup vs baseline: 1.0797x; 1.0626x over previous
//
#include <hip/hip_runtime.h>
#include <hip/hip_bf16.h>
#include <cstdint>

// VanillaLSTMCell: B=8192, I=H=1024.
// z = [x|h] @ [Wx;Wh]^T + b  (M=8192, N=4096, K=2048).
// W packed so each wave's four 16-col MFMA ni-tiles are the four GATES for the
// same 16 output columns: packed row n = (j>>4)*64 + gate*16 + (j&15).
// After the K-loop each lane holds all 4 gate pre-activations for its (row,j)
// in acc[mi][gate][r] -> LSTM pointwise runs register-resident, no LDS
// transpose, no extra barriers.

typedef __bf16 bf16;
typedef __attribute__((ext_vector_type(8))) bf16 bf16x8;
typedef __attribute__((ext_vector_type(4))) bf16 bf16x4;
typedef __attribute__((ext_vector_type(4))) float f32x4;

#define BM 128
#define BN 128
#define BK 32
#define CN_OFF 8388608  // 8192*1024, c_next offset in d_out

__device__ __forceinline__ void gload_lds16(const void* g, void* l) {
  __builtin_amdgcn_global_load_lds(
      (__attribute__((address_space(1))) void*)(void*)(g),
      (__attribute__((address_space(3))) void*)(void*)(l),
      16, 0, 0);
}

// ---- single pack kernel: blocks [0,16384) pack A; [16384,24576) pack W (+bias) ----
__global__ __launch_bounds__(256) void pack_all(
    const float* __restrict__ x, const float* __restrict__ h,
    const float* __restrict__ wxi, const float* __restrict__ whi,
    const float* __restrict__ wxf, const float* __restrict__ whf,
    const float* __restrict__ wxo, const float* __restrict__ who,
    const float* __restrict__ wxg, const float* __restrict__ whg,
    const float* __restrict__ bxi, const float* __restrict__ bhi,
    const float* __restrict__ bxf, const float* __restrict__ bhf,
    const float* __restrict__ bxo, const float* __restrict__ bho,
    const float* __restrict__ bxg, const float* __restrict__ bhg,
    bf16* __restrict__ A, bf16* __restrict__ W, float* __restrict__ Bcomb) {
  int b = blockIdx.x;
  if (b < 16384) {
    int idx = b * 256 + threadIdx.x;          // A: [8192][2048]
    int m = idx >> 9;
    int k = (idx & 511) * 4;
    const float* src = (k < 1024) ? (x + (size_t)m * 1024 + k)
                                  : (h + (size_t)m * 1024 + (k - 1024));
    f32x4 v = *(const f32x4*)src;
    bf16x4 o;
    o[0] = (bf16)v[0]; o[1] = (bf16)v[1]; o[2] = (bf16)v[2]; o[3] = (bf16)v[3];
    *(bf16x4*)(A + (size_t)idx * 4) = o;
  } else {
    int idx = (b - 16384) * 256 + threadIdx.x; // W: [4096][2048]
    int n = idx >> 9;
    int k = (idx & 511) * 4;
    // packed row n -> (gate, j): span p = n>>6 covers j in [p*16, p*16+16)
    int gate = (n >> 4) & 3;
    int j    = (n >> 6) * 16 + (n & 15);
    const float* wx = (gate == 0) ? wxi : (gate == 1) ? wxf : (gate == 2) ? wxo : wxg;
    const float* wh = (gate == 0) ? whi : (gate == 1) ? whf : (gate == 2) ? who : whg;
    const float* src = (k < 1024) ? (wx + (size_t)j * 1024 + k)
                                  : (wh + (size_t)j * 1024 + (k - 1024));
    f32x4 v = *(const f32x4*)src;
    bf16x4 o;
    o[0] = (bf16)v[0]; o[1] = (bf16)v[1]; o[2] = (bf16)v[2]; o[3] = (bf16)v[3];
    *(bf16x4*)(W + (size_t)idx * 4) = o;
    if ((idx & 511) == 0) {
      const float* bx = (gate == 0) ? bxi : (gate == 1) ? bxf : (gate == 2) ? bxo : bxg;
      const float* bh = (gate == 0) ? bhi : (gate == 1) ? bhf : (gate == 2) ? bho : bhg;
      Bcomb[n] = bx[j] + bh[j];
    }
  }
}

__device__ __forceinline__ float sigf(float v) { return 1.f / (1.f + __expf(-v)); }
__device__ __forceinline__ float tanhfast(float v) {
  v = fminf(15.f, fmaxf(-15.f, v));
  float e = __expf(2.f * v);
  return (e - 1.f) / (e + 1.f);
}

// ---- fused bf16 NT GEMM + register-resident LSTM epilogue ----
__global__ __launch_bounds__(256) void gemm_lstm(const bf16* __restrict__ A,
                                                 const bf16* __restrict__ W,
                                                 const float* __restrict__ Bcomb,
                                                 const float* __restrict__ c,
                                                 float* __restrict__ out) {
  constexpr int K = 2048;
  __shared__ __align__(16) bf16 As[BM * BK];   // 8 KB
  __shared__ __align__(16) bf16 Bs[BN * BK];   // 8 KB

  const int t    = threadIdx.x;
  const int wave = t >> 6;
  const int lane = t & 63;
  const int m0 = blockIdx.y * BM;
  const int n0 = blockIdx.x * BN;
  const int wm = (wave >> 1) * 64;
  const int wn = (wave & 1) * 64;
  const int lrow = lane & 15;
  const int lkg  = lane >> 4;

  f32x4 acc[4][4] = {};   // acc[mi][gate]

  const int arow = t >> 2;
  const int acol = (t & 3) * 8;
  const bf16* gA0 = A + (size_t)(m0 + arow) * K + acol;
  const bf16* gA1 = A + (size_t)(m0 + 64 + arow) * K + acol;
  const bf16* gB0 = W + (size_t)(n0 + arow) * K + acol;
  const bf16* gB1 = W + (size_t)(n0 + 64 + arow) * K + acol;
  bf16* lA0 = &As[t * 8];
  bf16* lA1 = &As[2048 + t * 8];
  bf16* lB0 = &Bs[t * 8];
  bf16* lB1 = &Bs[2048 + t * 8];

  for (int kt = 0; kt < K; kt += BK) {
    gload_lds16(gA0 + kt, lA0);
    gload_lds16(gA1 + kt, lA1);
    gload_lds16(gB0 + kt, lB0);
    gload_lds16(gB1 + kt, lB1);
    __syncthreads();

    bf16x8 a[4], b[4];
#pragma unroll
    for (int i = 0; i < 4; ++i) {
      a[i] = *(const bf16x8*)&As[(wm + i * 16 + lrow) * BK + lkg * 8];
      b[i] = *(const bf16x8*)&Bs[(wn + i * 16 + lrow) * BK + lkg * 8];
    }
#pragma unroll
    for (int mi = 0; mi < 4; ++mi)
#pragma unroll
      for (int ni = 0; ni < 4; ++ni)
        acc[mi][ni] = __builtin_amdgcn_mfma_f32_16x16x32_bf16(a[mi], b[ni], acc[mi][ni], 0, 0, 0);
    __syncthreads();
  }

  // ---- register-resident LSTM epilogue ----
  // Lane (lrow, lkg): j = jbase + lrow; rows = wm + mi*16 + lkg*4 + r.
  // acc[mi][gate][r] = z_gate for that (row, j). No LDS, no barriers.
  const int jg = (blockIdx.x * 2 + (wn >> 6)) * 16 + lrow;
  const float bi = Bcomb[n0 + wn +  0 + lrow];
  const float bf_ = Bcomb[n0 + wn + 16 + lrow];
  const float bo = Bcomb[n0 + wn + 32 + lrow];
  const float bg = Bcomb[n0 + wn + 48 + lrow];

#pragma unroll
  for (int mi = 0; mi < 4; ++mi) {
    const int row0 = m0 + wm + mi * 16 + lkg * 4;
    float cv[4];
#pragma unroll
    for (int r = 0; r < 4; ++r)
      cv[r] = c[(size_t)(row0 + r) * 1024 + jg];
#pragma unroll
    for (int r = 0; r < 4; ++r) {
      float zi = acc[mi][0][r] + bi;
      float zf = acc[mi][1][r] + bf_;
      float zo = acc[mi][2][r] + bo;
      float zg = acc[mi][3][r] + bg;
      float it = sigf(zi), ft = sigf(zf), ot = sigf(zo), gt = tanhfast(zg);
      float cn = ft * cv[r] + it * gt;
      size_t off = (size_t)(row0 + r) * 1024 + jg;
      out[off] = ot * tanhfast(cn);        // h_next
      out[CN_OFF + off] = cn;              // c_next
    }
  }
}

extern "C" void kernel_launch(void* const* d_in, const int* in_sizes, int n_in,
                              void* d_out, int out_size, void* d_ws, size_t ws_size,
                              hipStream_t stream) {
  const float* x   = (const float*)d_in[0];
  const float* h   = (const float*)d_in[1];
  const float* c   = (const float*)d_in[2];
  const float* Wxi = (const float*)d_in[3];  const float* bxi = (const float*)d_in[4];
  const float* Whi = (const float*)d_in[5];  const float* bhi = (const float*)d_in[6];
  const float* Wxf = (const float*)d_in[7];  const float* bxf = (const float*)d_in[8];
  const float* Whf = (const float*)d_in[9];  const float* bhf = (const float*)d_in[10];
  const float* Wxo = (const float*)d_in[11]; const float* bxo = (const float*)d_in[12];
  const float* Who = (const float*)d_in[13]; const float* bho = (const float*)d_in[14];
  const float* Wxg = (const float*)d_in[15]; const float* bxg = (const float*)d_in[16];
  const float* Whg = (const float*)d_in[17]; const float* bhg = (const float*)d_in[18];
  float* out = (float*)d_out;

  bf16*  Abuf  = (bf16*)d_ws;                          // 32 MB
  bf16*  Wbuf  = Abuf + (size_t)8192 * 2048;           // 16 MB
  float* Bcomb = (float*)(Wbuf + (size_t)4096 * 2048); // 16 KB

  pack_all<<<24576, 256, 0, stream>>>(x, h,
                                      Wxi, Whi, Wxf, Whf, Wxo, Who, Wxg, Whg,
                                      bxi, bhi, bxf, bhf, bxo, bho, bxg, bhg,
                                      Abuf, Wbuf, Bcomb);
  gemm_lstm<<<dim3(32, 64), 256, 0, stream>>>(Abuf, Wbuf, Bcomb, c, out);
}

// Round 5
// 355.296 us; speedup vs baseline: 1.1496x; 1.0648x over previous
//
#include <hip/hip_runtime.h>
#include <hip/hip_bf16.h>
#include <cstdint>

// VanillaLSTMCell: B=8192, I=H=1024.
// z = [x|h] @ [Wx;Wh]^T + b  (M=8192, N=4096, K=2048), LSTM pointwise fused.
//
// ROUND 5: barrier-free GEMM. A and W are packed in MFMA-FRAGMENT-MAJOR order
//   [tile][kt][wave_half][frag][lane][8bf16]
// so each wave loads its fragments with coalesced global_load_dwordx4 DIRECTLY
// into VGPRs -- no LDS, no __syncthreads in the K-loop, fine-grained vmcnt
// waits only (the AITER-style structure the m97 2-barrier loop can't express).
// Gate mapping folded into W pack: ni == gate for 16 j's per wave tile ->
// register-resident LSTM epilogue (round 4).

typedef __bf16 bf16;
typedef __attribute__((ext_vector_type(8))) bf16 bf16x8;
typedef __attribute__((ext_vector_type(4))) float f32x4;

#define CN_OFF 8388608  // 8192*1024, c_next offset in d_out

// ---- pack kernel ----
// blocks [0,8192):    A2[mb(64)][kt(64)][wm(2)][mi(4)][lane(64)][8]
//                     m = mb*128 + wm*64 + mi*16 + (lane&15), k = kt*32 + (lane>>4)*8
// blocks [8192,12288): B2[nb(32)][kt(64)][wn(2)][gate(4)][lane(64)][8]
//                     j = (nb*2+wn)*16 + (lane&15), k = kt*32 + (lane>>4)*8
// Bias: Bcomb[(nb*2+wn)*64 + gate*16 + jl] = bx[j]+bh[j]
__global__ __launch_bounds__(256) void pack_all(
    const float* __restrict__ x, const float* __restrict__ h,
    const float* __restrict__ wxi, const float* __restrict__ whi,
    const float* __restrict__ wxf, const float* __restrict__ whf,
    const float* __restrict__ wxo, const float* __restrict__ who,
    const float* __restrict__ wxg, const float* __restrict__ whg,
    const float* __restrict__ bxi, const float* __restrict__ bhi,
    const float* __restrict__ bxf, const float* __restrict__ bhf,
    const float* __restrict__ bxo, const float* __restrict__ bho,
    const float* __restrict__ bxg, const float* __restrict__ bhg,
    bf16* __restrict__ A2, bf16* __restrict__ B2, float* __restrict__ Bcomb) {
  int b = blockIdx.x;
  if (b < 8192) {
    int chunk = b * 256 + threadIdx.x;        // 2,097,152 chunks of 8
    int lane = chunk & 63;
    int mi   = (chunk >> 6) & 3;
    int wm   = (chunk >> 8) & 1;
    int kt   = (chunk >> 9) & 63;
    int mb   = chunk >> 15;
    int m = mb * 128 + wm * 64 + mi * 16 + (lane & 15);
    int k = kt * 32 + (lane >> 4) * 8;
    const float* src = (k < 1024) ? (x + (size_t)m * 1024 + k)
                                  : (h + (size_t)m * 1024 + (k - 1024));
    f32x4 v0 = *(const f32x4*)src;
    f32x4 v1 = *(const f32x4*)(src + 4);
    bf16x8 o;
    o[0]=(bf16)v0[0]; o[1]=(bf16)v0[1]; o[2]=(bf16)v0[2]; o[3]=(bf16)v0[3];
    o[4]=(bf16)v1[0]; o[5]=(bf16)v1[1]; o[6]=(bf16)v1[2]; o[7]=(bf16)v1[3];
    *(bf16x8*)(A2 + (size_t)chunk * 8) = o;
  } else {
    int chunk = (b - 8192) * 256 + threadIdx.x;  // 1,048,576 chunks of 8
    int lane = chunk & 63;
    int gate = (chunk >> 6) & 3;
    int wn   = (chunk >> 8) & 1;
    int kt   = (chunk >> 9) & 63;
    int nb   = chunk >> 15;
    int jl = lane & 15;
    int j  = (nb * 2 + wn) * 16 + jl;
    int k  = kt * 32 + (lane >> 4) * 8;
    const float* wx = (gate == 0) ? wxi : (gate == 1) ? wxf : (gate == 2) ? wxo : wxg;
    const float* wh = (gate == 0) ? whi : (gate == 1) ? whf : (gate == 2) ? who : whg;
    const float* src = (k < 1024) ? (wx + (size_t)j * 1024 + k)
                                  : (wh + (size_t)j * 1024 + (k - 1024));
    f32x4 v0 = *(const f32x4*)src;
    f32x4 v1 = *(const f32x4*)(src + 4);
    bf16x8 o;
    o[0]=(bf16)v0[0]; o[1]=(bf16)v0[1]; o[2]=(bf16)v0[2]; o[3]=(bf16)v0[3];
    o[4]=(bf16)v1[0]; o[5]=(bf16)v1[1]; o[6]=(bf16)v1[2]; o[7]=(bf16)v1[3];
    *(bf16x8*)(B2 + (size_t)chunk * 8) = o;
    if (kt == 0 && (lane >> 4) == 0) {
      const float* bx = (gate == 0) ? bxi : (gate == 1) ? bxf : (gate == 2) ? bxo : bxg;
      const float* bh = (gate == 0) ? bhi : (gate == 1) ? bhf : (gate == 2) ? bho : bhg;
      Bcomb[(nb * 2 + wn) * 64 + gate * 16 + jl] = bx[j] + bh[j];
    }
  }
}

__device__ __forceinline__ float sigf(float v) { return 1.f / (1.f + __expf(-v)); }
__device__ __forceinline__ float tanhfast(float v) {
  v = fminf(15.f, fmaxf(-15.f, v));
  float e = __expf(2.f * v);
  return (e - 1.f) / (e + 1.f);
}

// ---- barrier-free fragment-direct GEMM + register-resident LSTM epilogue ----
__global__ __launch_bounds__(256) void gemm_lstm(const bf16* __restrict__ A2,
                                                 const bf16* __restrict__ B2,
                                                 const float* __restrict__ Bcomb,
                                                 const float* __restrict__ c,
                                                 float* __restrict__ out) {
  const int t    = threadIdx.x;
  const int wave = t >> 6;
  const int lane = t & 63;
  const int nb = blockIdx.x;     // 32 N-tiles
  const int mb = blockIdx.y;     // 64 M-tiles
  const int wm = wave >> 1;      // wave's 64-row half
  const int wn = wave & 1;       // wave's 64-col half
  const int lrow = lane & 15;
  const int lkg  = lane >> 4;

  // fragment-major bases: offset(kt,frag) = kt*4096 + frag*512 (elements)
  const bf16* pa = A2 + (size_t)mb * 262144 + wm * 2048 + lane * 8;
  const bf16* pb = B2 + (size_t)nb * 262144 + wn * 2048 + lane * 8;

  f32x4 acc[4][4] = {};   // acc[mi][gate]
  bf16x8 a0[4], b0[4], a1[4], b1[4];

#pragma unroll
  for (int i = 0; i < 4; ++i) {
    a0[i] = *(const bf16x8*)(pa + i * 512);
    b0[i] = *(const bf16x8*)(pb + i * 512);
  }
#pragma unroll
  for (int i = 0; i < 4; ++i) {
    a1[i] = *(const bf16x8*)(pa + 4096 + i * 512);
    b1[i] = *(const bf16x8*)(pb + 4096 + i * 512);
  }

  for (int kt = 0; kt < 64; kt += 2) {
#pragma unroll
    for (int mi = 0; mi < 4; ++mi)
#pragma unroll
      for (int ni = 0; ni < 4; ++ni)
        acc[mi][ni] = __builtin_amdgcn_mfma_f32_16x16x32_bf16(a0[mi], b0[ni], acc[mi][ni], 0, 0, 0);
    if (kt + 2 < 64) {
      const bf16* qa = pa + (size_t)(kt + 2) * 4096;
      const bf16* qb = pb + (size_t)(kt + 2) * 4096;
#pragma unroll
      for (int i = 0; i < 4; ++i) {
        a0[i] = *(const bf16x8*)(qa + i * 512);
        b0[i] = *(const bf16x8*)(qb + i * 512);
      }
    }
#pragma unroll
    for (int mi = 0; mi < 4; ++mi)
#pragma unroll
      for (int ni = 0; ni < 4; ++ni)
        acc[mi][ni] = __builtin_amdgcn_mfma_f32_16x16x32_bf16(a1[mi], b1[ni], acc[mi][ni], 0, 0, 0);
    if (kt + 3 < 64) {
      const bf16* qa = pa + (size_t)(kt + 3) * 4096;
      const bf16* qb = pb + (size_t)(kt + 3) * 4096;
#pragma unroll
      for (int i = 0; i < 4; ++i) {
        a1[i] = *(const bf16x8*)(qa + i * 512);
        b1[i] = *(const bf16x8*)(qb + i * 512);
      }
    }
  }

  // ---- register-resident LSTM epilogue (round-4 mapping) ----
  // Lane (lrow,lkg): j = (nb*2+wn)*16 + lrow; rows = mb*128 + wm*64 + mi*16 + lkg*4 + r
  const int jg = (nb * 2 + wn) * 16 + lrow;
  const int bbase = (nb * 2 + wn) * 64 + lrow;
  const float bi  = Bcomb[bbase +  0];
  const float bf_ = Bcomb[bbase + 16];
  const float bo  = Bcomb[bbase + 32];
  const float bg  = Bcomb[bbase + 48];

#pragma unroll
  for (int mi = 0; mi < 4; ++mi) {
    const int row0 = mb * 128 + wm * 64 + mi * 16 + lkg * 4;
    float cv[4];
#pragma unroll
    for (int r = 0; r < 4; ++r)
      cv[r] = c[(size_t)(row0 + r) * 1024 + jg];
#pragma unroll
    for (int r = 0; r < 4; ++r) {
      float zi = acc[mi][0][r] + bi;
      float zf = acc[mi][1][r] + bf_;
      float zo = acc[mi][2][r] + bo;
      float zg = acc[mi][3][r] + bg;
      float it = sigf(zi), ft = sigf(zf), ot = sigf(zo), gt = tanhfast(zg);
      float cn = ft * cv[r] + it * gt;
      size_t off = (size_t)(row0 + r) * 1024 + jg;
      out[off] = ot * tanhfast(cn);        // h_next
      out[CN_OFF + off] = cn;              // c_next
    }
  }
}

extern "C" void kernel_launch(void* const* d_in, const int* in_sizes, int n_in,
                              void* d_out, int out_size, void* d_ws, size_t ws_size,
                              hipStream_t stream) {
  const float* x   = (const float*)d_in[0];
  const float* h   = (const float*)d_in[1];
  const float* c   = (const float*)d_in[2];
  const float* Wxi = (const float*)d_in[3];  const float* bxi = (const float*)d_in[4];
  const float* Whi = (const float*)d_in[5];  const float* bhi = (const float*)d_in[6];
  const float* Wxf = (const float*)d_in[7];  const float* bxf = (const float*)d_in[8];
  const float* Whf = (const float*)d_in[9];  const float* bhf = (const float*)d_in[10];
  const float* Wxo = (const float*)d_in[11]; const float* bxo = (const float*)d_in[12];
  const float* Who = (const float*)d_in[13]; const float* bho = (const float*)d_in[14];
  const float* Wxg = (const float*)d_in[15]; const float* bxg = (const float*)d_in[16];
  const float* Whg = (const float*)d_in[17]; const float* bhg = (const float*)d_in[18];
  float* out = (float*)d_out;

  bf16*  Abuf  = (bf16*)d_ws;                          // 32 MB
  bf16*  Wbuf  = Abuf + (size_t)8192 * 2048;           // 16 MB
  float* Bcomb = (float*)(Wbuf + (size_t)4096 * 2048); // 16 KB

  pack_all<<<12288, 256, 0, stream>>>(x, h,
                                      Wxi, Whi, Wxf, Whf, Wxo, Who, Wxg, Whg,
                                      bxi, bhi, bxf, bhf, bxo, bho, bxg, bhg,
                                      Abuf, Wbuf, Bcomb);
  gemm_lstm<<<dim3(32, 64), 256, 0, stream>>>(Abuf, Wbuf, Bcomb, c, out);
}